// Round 7
// baseline (702.072 us; speedup 1.0000x reference)
//
#include <hip/hip_runtime.h>
#include <hip/hip_bf16.h>

// Problem dims
#define BB 64
#define TT 128
#define FIN 12
#define HH 128
#define BT 16    // batches per lstm block (MFMA N)
#define SROW 136 // sbuf row stride in bf16: 272B/row, 16B-aligned, 2-way banks

#define LOG2E 1.4426950408889634f
#define TWO_LOG2E 2.8853900817779268f

typedef __attribute__((ext_vector_type(8))) short bf16x8;
typedef __attribute__((ext_vector_type(4))) float f32x4;

#define MFMA(a, b, c) __builtin_amdgcn_mfma_f32_16x16x32_bf16((a), (b), (c), 0, 0, 0)

__device__ __forceinline__ float fexp2(float x) { return __builtin_amdgcn_exp2f(x); }
__device__ __forceinline__ float frcp(float x)  { return __builtin_amdgcn_rcpf(x); }

__device__ __forceinline__ float tanh_f(float x) {
  return 1.0f - 2.0f * frcp(1.0f + fexp2(TWO_LOG2E * x));
}
__device__ __forceinline__ float sigm_f(float x) {
  return frcp(1.0f + fexp2(-LOG2E * x));
}

// bf16 round-to-nearest-even + hi/lo split (hi+lo ~ fp32-exact)
__device__ __forceinline__ unsigned short bfhi(float v) {
  unsigned u = __float_as_uint(v);
  return (unsigned short)((u + 0x7FFFu + ((u >> 16) & 1u)) >> 16);
}
__device__ __forceinline__ float bf2f(unsigned short h) {
  return __uint_as_float((unsigned)h << 16);
}
__device__ __forceinline__ void bfsplit(float v, unsigned short& hi, unsigned short& lo) {
  hi = bfhi(v);
  lo = bfhi(v - bf2f(hi));
}

#define FMA4S(acc, s, v) do { \
  acc.x = fmaf((s), (v).x, acc.x); \
  acc.y = fmaf((s), (v).y, acc.y); \
  acc.z = fmaf((s), (v).z, acc.z); \
  acc.w = fmaf((s), (v).w, acc.w); } while (0)

// ---------------------------------------------------------------------------
// K1 v7: MFMA recurrence. 4 blocks x 512 thr; block owns 16 batches.
// Per step: z(512x16) = [Whh | Wih | b](512x160) @ [h; x_t; 1](160x16) via
// 16x16x32 bf16 MFMA, hi/lo split (3 terms) for fp32-grade accuracy.
// Wave w owns gate-rows {g*128+16w..+16} for g=i,f,g~,o; C-layout gives each
// lane 4 rows x 1 batch of every gate -> activations, c and h update fully
// in-register (no cross-lane reduce). h round-trips through LDS (bf16 hi/lo,
// double-buffered); x + bias-slot fragments built from registers. 1 barrier
// per step; h(t-1) global store issued early so the barrier vmcnt is pre-acked
// (R3-R6 lesson: per-step store acks and DS-pipe ops were the invariant cost).
// ---------------------------------------------------------------------------
__global__ __launch_bounds__(512, 2) void lstm_kernel(
    const float* __restrict__ x,
    const float* __restrict__ eWih, const float* __restrict__ eWhh, const float* __restrict__ eb,
    const float* __restrict__ dWih, const float* __restrict__ dWhh, const float* __restrict__ db,
    float* __restrict__ encH, float* __restrict__ decH)
{
  const int bb0  = blockIdx.x * BT;
  const int tid  = threadIdx.x;
  const int w    = tid >> 6;     // wave 0..7
  const int lane = tid & 63;
  const int bcol = lane & 15;    // batch col (B n-index, C col)
  const int quad = lane >> 4;

  __shared__ __align__(16) unsigned short sbuf[2][2][BT][SROW];  // [buf][hi/lo][b][k]

  // zero-fill sbuf (h(0)=0, pad zeros)
  {
    unsigned* p = (unsigned*)sbuf;
    for (int idx = tid; idx < (2 * 2 * BT * SROW / 2); idx += 512) p[idx] = 0;
  }

  // preload x(t=0) into regs
  float xc[8];
  {
    const float* xb = x + (size_t)(bb0 + bcol) * TT * FIN;
    if (quad == 0) {
      float4 a = *(const float4*)xb, b2 = *(const float4*)(xb + 4);
      xc[0]=a.x; xc[1]=a.y; xc[2]=a.z; xc[3]=a.w; xc[4]=b2.x; xc[5]=b2.y; xc[6]=b2.z; xc[7]=b2.w;
    } else if (quad == 1) {
      float4 a = *(const float4*)(xb + 8);
      xc[0]=a.x; xc[1]=a.y; xc[2]=a.z; xc[3]=a.w; xc[4]=0; xc[5]=0; xc[6]=0; xc[7]=0;
    } else {
      #pragma unroll
      for (int j = 0; j < 8; ++j) xc[j] = 0.0f;
    }
  }
  __syncthreads();  // sbuf zeros visible

  const int arow = w * 16 + (lane & 15);  // A m-row within each gate block

  float c0 = 0.f, c1 = 0.f, c2 = 0.f, c3 = 0.f;     // cell state (4 rows x 1 batch)
  float hp0 = 0.f, hp1 = 0.f, hp2 = 0.f, hp3 = 0.f; // h(ts-1) pending store

  #pragma unroll 1
  for (int phase = 0; phase < 2; ++phase) {
    const float* Wih  = phase ? dWih : eWih;
    const float* Whh  = phase ? dWhh : eWhh;
    const float* bias = phase ? db : eb;

    // ---- load A fragments for this phase: 4 gates x 5 k-tiles x {hi,lo} ----
    bf16x8 Ahi[4][5], Alo[4][5];
    #pragma unroll
    for (int g = 0; g < 4; ++g) {
      const float* wr = Whh + (size_t)(g * HH + arow) * HH + quad * 8;
      #pragma unroll
      for (int kt = 0; kt < 4; ++kt) {
        float4 v0 = *(const float4*)(wr + kt * 32);
        float4 v1 = *(const float4*)(wr + kt * 32 + 4);
        float vv[8] = {v0.x, v0.y, v0.z, v0.w, v1.x, v1.y, v1.z, v1.w};
        bf16x8 h8, l8;
        #pragma unroll
        for (int j = 0; j < 8; ++j) {
          unsigned short hi, lo; bfsplit(vv[j], hi, lo);
          h8[j] = (short)hi; l8[j] = (short)lo;
        }
        Ahi[g][kt] = h8; Alo[g][kt] = l8;
      }
      {  // kt=4: k=128..159 -> [x (12) | bias (k=140) | 0]
        float vv[8] = {0, 0, 0, 0, 0, 0, 0, 0};
        if (quad == 0) {
          const float* wir = Wih + (size_t)(g * HH + arow) * FIN;
          #pragma unroll
          for (int j = 0; j < 8; ++j) vv[j] = wir[j];
        } else if (quad == 1) {
          const float* wir = Wih + (size_t)(g * HH + arow) * FIN + 8;
          #pragma unroll
          for (int j = 0; j < 4; ++j) vv[j] = wir[j];
          vv[4] = bias[g * HH + arow];
        }
        bf16x8 h8, l8;
        #pragma unroll
        for (int j = 0; j < 8; ++j) {
          unsigned short hi, lo; bfsplit(vv[j], hi, lo);
          h8[j] = (short)hi; l8[j] = (short)lo;
        }
        Ahi[g][4] = h8; Alo[g][4] = l8;
      }
    }

    #pragma unroll 1
    for (int t = 0; t < TT; ++t) {
      const int ts  = phase * TT + t;
      const int cur = ts & 1, nxt = cur ^ 1;
      __syncthreads();  // sbuf[cur] = h(ts) ready; prev reads of sbuf[nxt] done

      // 1. store h(ts-1) early (ack lands before next barrier)
      if (ts > 0) {
        const int tsp = ts - 1;
        float* Hp = (tsp >> 7) ? decH : encH;
        *(float4*)(Hp + ((size_t)(bb0 + bcol) * TT + (tsp & 127)) * HH + w * 16 + quad * 4)
            = make_float4(hp0, hp1, hp2, hp3);
      }

      // 2. prefetch x for next step
      float xn[8] = {0, 0, 0, 0, 0, 0, 0, 0};
      {
        const int tn = (ts + 1) & 127;
        const float* xb = x + (size_t)(bb0 + bcol) * TT * FIN + tn * FIN;
        if (quad == 0) {
          float4 a = *(const float4*)xb, b2 = *(const float4*)(xb + 4);
          xn[0]=a.x; xn[1]=a.y; xn[2]=a.z; xn[3]=a.w; xn[4]=b2.x; xn[5]=b2.y; xn[6]=b2.z; xn[7]=b2.w;
        } else if (quad == 1) {
          float4 a = *(const float4*)(xb + 8);
          xn[0]=a.x; xn[1]=a.y; xn[2]=a.z; xn[3]=a.w;
        }
      }

      // 3. build B fragment for kt=4 from xc regs: [x | 1.0 @k=140 | 0]
      bf16x8 bxh = {0,0,0,0,0,0,0,0}, bxl = {0,0,0,0,0,0,0,0};
      if (quad == 0) {
        #pragma unroll
        for (int j = 0; j < 8; ++j) {
          unsigned short hi, lo; bfsplit(xc[j], hi, lo);
          bxh[j] = (short)hi; bxl[j] = (short)lo;
        }
      } else if (quad == 1) {
        #pragma unroll
        for (int j = 0; j < 4; ++j) {
          unsigned short hi, lo; bfsplit(xc[j], hi, lo);
          bxh[j] = (short)hi; bxl[j] = (short)lo;
        }
        bxh[4] = (short)0x3F80;  // 1.0 -> bias column
      }

      // 4. k-streamed MFMA: 3-term split products
      f32x4 acc0 = {0,0,0,0}, acc1 = {0,0,0,0}, acc2 = {0,0,0,0}, acc3 = {0,0,0,0};
      const unsigned short* sb_hi = &sbuf[cur][0][bcol][quad * 8];
      const unsigned short* sb_lo = &sbuf[cur][1][bcol][quad * 8];
      #pragma unroll
      for (int kt = 0; kt < 4; ++kt) {
        bf16x8 bh = *(const bf16x8*)(sb_hi + kt * 32);
        bf16x8 bl = *(const bf16x8*)(sb_lo + kt * 32);
        acc0 = MFMA(Ahi[0][kt], bh, acc0); acc1 = MFMA(Ahi[1][kt], bh, acc1);
        acc2 = MFMA(Ahi[2][kt], bh, acc2); acc3 = MFMA(Ahi[3][kt], bh, acc3);
        acc0 = MFMA(Alo[0][kt], bh, acc0); acc1 = MFMA(Alo[1][kt], bh, acc1);
        acc2 = MFMA(Alo[2][kt], bh, acc2); acc3 = MFMA(Alo[3][kt], bh, acc3);
        acc0 = MFMA(Ahi[0][kt], bl, acc0); acc1 = MFMA(Ahi[1][kt], bl, acc1);
        acc2 = MFMA(Ahi[2][kt], bl, acc2); acc3 = MFMA(Ahi[3][kt], bl, acc3);
      }
      acc0 = MFMA(Ahi[0][4], bxh, acc0); acc1 = MFMA(Ahi[1][4], bxh, acc1);
      acc2 = MFMA(Ahi[2][4], bxh, acc2); acc3 = MFMA(Ahi[3][4], bxh, acc3);
      acc0 = MFMA(Alo[0][4], bxh, acc0); acc1 = MFMA(Alo[1][4], bxh, acc1);
      acc2 = MFMA(Alo[2][4], bxh, acc2); acc3 = MFMA(Alo[3][4], bxh, acc3);
      acc0 = MFMA(Ahi[0][4], bxl, acc0); acc1 = MFMA(Ahi[1][4], bxl, acc1);
      acc2 = MFMA(Ahi[2][4], bxl, acc2); acc3 = MFMA(Ahi[3][4], bxl, acc3);

      // 5. activations + cell update (rows w*16+quad*4+r, batch bcol)
      unsigned short hh[4], hl[4];
      {
        float zi, zf, zg, zo;
        zi = sigm_f(acc0[0]); zf = sigm_f(acc1[0]); zg = tanh_f(acc2[0]); zo = sigm_f(acc3[0]);
        c0 = fmaf(zf, c0, zi * zg); hp0 = zo * tanh_f(c0); bfsplit(hp0, hh[0], hl[0]);
        zi = sigm_f(acc0[1]); zf = sigm_f(acc1[1]); zg = tanh_f(acc2[1]); zo = sigm_f(acc3[1]);
        c1 = fmaf(zf, c1, zi * zg); hp1 = zo * tanh_f(c1); bfsplit(hp1, hh[1], hl[1]);
        zi = sigm_f(acc0[2]); zf = sigm_f(acc1[2]); zg = tanh_f(acc2[2]); zo = sigm_f(acc3[2]);
        c2 = fmaf(zf, c2, zi * zg); hp2 = zo * tanh_f(c2); bfsplit(hp2, hh[2], hl[2]);
        zi = sigm_f(acc0[3]); zf = sigm_f(acc1[3]); zg = tanh_f(acc2[3]); zo = sigm_f(acc3[3]);
        c3 = fmaf(zf, c3, zi * zg); hp3 = zo * tanh_f(c3); bfsplit(hp3, hh[3], hl[3]);
      }

      // 6. write h(ts+1-state) hi/lo to sbuf[nxt] (4 consecutive bf16 = b64)
      {
        unsigned long long ph = (unsigned long long)hh[0] | ((unsigned long long)hh[1] << 16)
                              | ((unsigned long long)hh[2] << 32) | ((unsigned long long)hh[3] << 48);
        unsigned long long pl = (unsigned long long)hl[0] | ((unsigned long long)hl[1] << 16)
                              | ((unsigned long long)hl[2] << 32) | ((unsigned long long)hl[3] << 48);
        *(unsigned long long*)&sbuf[nxt][0][bcol][w * 16 + quad * 4] = ph;
        *(unsigned long long*)&sbuf[nxt][1][bcol][w * 16 + quad * 4] = pl;
      }

      // 7. roll x regs
      #pragma unroll
      for (int j = 0; j < 8; ++j) xc[j] = xn[j];
    }
  }
  // final store h(255)
  *(float4*)(decH + ((size_t)(bb0 + bcol) * TT + 127) * HH + w * 16 + quad * 4)
      = make_float4(hp0, hp1, hp2, hp3);
}

// ---------------------------------------------------------------------------
// K2: A[b,s,h] = decH[b,s,:]·W1[h,:] + attn_b[h]   (m==0)
//     P[b,t,h] = encH[b,t,:]·W2[h,:]               (m==1)
// grid 1024 = (8 row-tiles x 64 b x 2 m), 256 threads, k-halved LDS W^T.
// ---------------------------------------------------------------------------
__global__ __launch_bounds__(256, 2) void proj_kernel(
    const float* __restrict__ encH, const float* __restrict__ decH,
    const float* __restrict__ attnW, const float* __restrict__ attnb,
    float* __restrict__ Abuf, float* __restrict__ Pbuf)
{
  const int m  = blockIdx.x & 1;
  const int b  = (blockIdx.x >> 1) & 63;
  const int r0 = (blockIdx.x >> 7) * 16;
  const int tid = threadIdx.x;

  __shared__ __align__(16) float WT[64 * 128];  // 32 KB: W^T for a k-half
  __shared__ __align__(16) float Xt[16 * 128];  // 8 KB

  const float* X = (m ? encH : decH) + ((size_t)b * TT + r0) * HH;
  const float* W = attnW + (m ? HH : 0);

  ((float4*)Xt)[tid]       = ((const float4*)X)[tid];
  ((float4*)Xt)[256 + tid] = ((const float4*)X)[256 + tid];

  const int hq = tid & 31, rr = tid >> 5;
  const int h0 = 4 * hq;

  float4 acc0, acc1;
  if (m == 0) { acc0 = *(const float4*)(attnb + h0); acc1 = acc0; }
  else        { acc0 = make_float4(0.f, 0.f, 0.f, 0.f); acc1 = acc0; }

  for (int kb = 0; kb < 2; ++kb) {
    __syncthreads();  // protect WT overwrite
    {
      int h = tid >> 1, koff = (tid & 1) * 32;
      #pragma unroll
      for (int j = 0; j < 8; ++j) {
        float4 v = *(const float4*)(W + h * 256 + kb * 64 + koff + 4 * j);
        int kp = koff + 4 * j;
        WT[(kp + 0) * 128 + h] = v.x;
        WT[(kp + 1) * 128 + h] = v.y;
        WT[(kp + 2) * 128 + h] = v.z;
        WT[(kp + 3) * 128 + h] = v.w;
      }
    }
    __syncthreads();
    const float* xr0 = Xt + (2 * rr) * 128 + kb * 64;
    const float* xr1 = xr0 + 128;
    #pragma unroll
    for (int k4 = 0; k4 < 64; k4 += 4) {
      float4 xa = *(const float4*)(xr0 + k4);
      float4 xb = *(const float4*)(xr1 + k4);
      float4 w0 = *(const float4*)&WT[(k4 + 0) * 128 + h0];
      float4 w1 = *(const float4*)&WT[(k4 + 1) * 128 + h0];
      float4 w2 = *(const float4*)&WT[(k4 + 2) * 128 + h0];
      float4 w3 = *(const float4*)&WT[(k4 + 3) * 128 + h0];
      FMA4S(acc0, xa.x, w0); FMA4S(acc0, xa.y, w1);
      FMA4S(acc0, xa.z, w2); FMA4S(acc0, xa.w, w3);
      FMA4S(acc1, xb.x, w0); FMA4S(acc1, xb.y, w1);
      FMA4S(acc1, xb.z, w2); FMA4S(acc1, xb.w, w3);
    }
  }
  float* O = (m ? Pbuf : Abuf) + ((size_t)b * TT + r0) * HH;
  *(float4*)(O + (2 * rr) * 128 + h0)     = acc0;
  *(float4*)(O + (2 * rr + 1) * 128 + h0) = acc1;
}

// ---------------------------------------------------------------------------
// K3: attention + output. Block = (b, 16 decoder steps). 512 threads.
// t halved so LDS stays < 64 KB; P transposed into LDS with XOR-quad swizzle.
// ---------------------------------------------------------------------------
__global__ __launch_bounds__(512, 2) void attn_kernel(
    const float* __restrict__ encH, const float* __restrict__ decH,
    const float* __restrict__ Abuf, const float* __restrict__ Pbuf,
    const float* __restrict__ vw, const float* __restrict__ outW,
    const float* __restrict__ outb, float* __restrict__ out)
{
  const int b  = blockIdx.x >> 3;
  const int s0 = (blockIdx.x & 7) * 16;
  const int tid = threadIdx.x;

  __shared__ __align__(16) float buf[64 * 128];    // 32 KB: P^T-half (swizzled), later encH-half
  __shared__ __align__(16) float a_lds[16 * 128];  // 8 KB: A tile, later ctx
  __shared__ __align__(16) float sc[16 * 128];     // 8 KB: scores -> weights
  __shared__ __align__(16) float dh[16 * 128];     // 8 KB: decH tile
  __shared__ __align__(16) float vl[HH];

  ((float4*)a_lds)[tid] = ((const float4*)(Abuf + ((size_t)b * TT + s0) * HH))[tid];
  ((float4*)dh)[tid]    = ((const float4*)(decH + ((size_t)b * TT + s0) * HH))[tid];
  if (tid < 32) ((float4*)vl)[tid] = ((const float4*)vw)[tid];

  const int u  = tid & 31;
  const int sl = tid >> 5;   // 0..15 decoder-step within tile
  const int uq = u & 15;     // t-quad within half
  const int uh = u >> 4;     // 0/1 h-half

  // ---- energies/scores ----
  for (int half = 0; half < 2; ++half) {
    const int tbase = half * 64;
    __syncthreads();  // prev buf use done (also covers initial staging)
    #pragma unroll
    for (int i = 0; i < 4; ++i) {
      int flat = i * 2048 + tid * 4;
      int tp = flat >> 7;        // 0..63
      int h0 = flat & 127;
      float4 v = *(const float4*)(Pbuf + ((size_t)b * TT + tbase + tp) * HH + h0);
      int tq = tp >> 2, tr = tp & 3;
      buf[(h0 + 0) * 64 + 4 * ((tq ^ ((h0 + 0) >> 2)) & 15) + tr] = v.x;
      buf[(h0 + 1) * 64 + 4 * ((tq ^ ((h0 + 1) >> 2)) & 15) + tr] = v.y;
      buf[(h0 + 2) * 64 + 4 * ((tq ^ ((h0 + 2) >> 2)) & 15) + tr] = v.z;
      buf[(h0 + 3) * 64 + 4 * ((tq ^ ((h0 + 3) >> 2)) & 15) + tr] = v.w;
    }
    __syncthreads();
    float4 acc = make_float4(0.f, 0.f, 0.f, 0.f);
    const float* arow = a_lds + sl * 128;
    #pragma unroll 8
    for (int hh = 0; hh < 64; ++hh) {
      int h = uh * 64 + hh;
      float ah = arow[h];
      float vh = vl[h];
      float4 p4 = *(const float4*)&buf[h * 64 + 4 * ((uq ^ ((h >> 2) & 15)) & 15)];
      acc.x = fmaf(vh, tanh_f(ah + p4.x), acc.x);
      acc.y = fmaf(vh, tanh_f(ah + p4.y), acc.y);
      acc.z = fmaf(vh, tanh_f(ah + p4.z), acc.z);
      acc.w = fmaf(vh, tanh_f(ah + p4.w), acc.w);
    }
    acc.x += __shfl_xor(acc.x, 16, 64);
    acc.y += __shfl_xor(acc.y, 16, 64);
    acc.z += __shfl_xor(acc.z, 16, 64);
    acc.w += __shfl_xor(acc.w, 16, 64);
    if (uh == 0) *(float4*)&sc[sl * 128 + tbase + 4 * uq] = acc;
  }
  __syncthreads();

  // ---- softmax over t (per s row; 32 lanes x f4 = 128) ----
  {
    float4 sv = *(const float4*)&sc[sl * 128 + 4 * u];
    float mx = fmaxf(fmaxf(sv.x, sv.y), fmaxf(sv.z, sv.w));
    #pragma unroll
    for (int msk = 1; msk <= 16; msk <<= 1) mx = fmaxf(mx, __shfl_xor(mx, msk, 64));
    float4 e;
    e.x = fexp2(LOG2E * (sv.x - mx));
    e.y = fexp2(LOG2E * (sv.y - mx));
    e.z = fexp2(LOG2E * (sv.z - mx));
    e.w = fexp2(LOG2E * (sv.w - mx));
    float sm = (e.x + e.y) + (e.z + e.w);
    #pragma unroll
    for (int msk = 1; msk <= 16; msk <<= 1) sm += __shfl_xor(sm, msk, 64);
    float r = frcp(sm);
    e.x *= r; e.y *= r; e.z *= r; e.w *= r;
    *(float4*)&sc[sl * 128 + 4 * u] = e;
  }

  // ---- ctx = w @ encH ----
  float4 ctx = make_float4(0.f, 0.f, 0.f, 0.f);
  const int h0c = 4 * u;
  for (int half = 0; half < 2; ++half) {
    const int tbase = half * 64;
    __syncthreads();  // buf reuse; also orders softmax writes before reads
    #pragma unroll
    for (int i = 0; i < 4; ++i) {
      int flat = i * 2048 + tid * 4;
      int tp = flat >> 7;
      int hh0 = flat & 127;
      *(float4*)&buf[tp * 128 + hh0] =
          *(const float4*)(encH + ((size_t)b * TT + tbase + tp) * HH + hh0);
    }
    __syncthreads();
    const float* wrow = sc + sl * 128 + tbase;
    #pragma unroll 8
    for (int tp = 0; tp < 64; ++tp) {
      float wt = wrow[tp];
      float4 e4 = *(const float4*)&buf[tp * 128 + h0c];
      FMA4S(ctx, wt, e4);
    }
  }
  __syncthreads();
  *(float4*)&a_lds[sl * 128 + h0c] = ctx;  // overlay A tile with ctx
  __syncthreads();

  // ---- out = [decH, ctx] @ outW^T + outb ----
  if (tid < 192) {
    int s = tid / 12, f = tid % 12;
    float acc = outb[f];
    const float4* w4 = (const float4*)(outW + f * 256);
    const float4* d4 = (const float4*)(dh + s * 128);
    const float4* c4 = (const float4*)(a_lds + s * 128);
    #pragma unroll
    for (int k = 0; k < 32; ++k) {
      float4 wv = w4[k], dv = d4[k];
      acc = fmaf(wv.x, dv.x, acc); acc = fmaf(wv.y, dv.y, acc);
      acc = fmaf(wv.z, dv.z, acc); acc = fmaf(wv.w, dv.w, acc);
    }
    #pragma unroll
    for (int k = 0; k < 32; ++k) {
      float4 wv = w4[32 + k], cv = c4[k];
      acc = fmaf(wv.x, cv.x, acc); acc = fmaf(wv.y, cv.y, acc);
      acc = fmaf(wv.z, cv.z, acc); acc = fmaf(wv.w, cv.w, acc);
    }
    out[((size_t)b * TT + s0 + s) * FIN + f] = acc;
  }
}

// ---------------------------------------------------------------------------
extern "C" void kernel_launch(void* const* d_in, const int* in_sizes, int n_in,
                              void* d_out, int out_size, void* d_ws, size_t ws_size,
                              hipStream_t stream)
{
  const float* x     = (const float*)d_in[0];
  const float* eWih  = (const float*)d_in[1];
  const float* eWhh  = (const float*)d_in[2];
  const float* eb    = (const float*)d_in[3];
  const float* dWih  = (const float*)d_in[4];
  const float* dWhh  = (const float*)d_in[5];
  const float* db    = (const float*)d_in[6];
  const float* attnW = (const float*)d_in[7];
  const float* attnb = (const float*)d_in[8];
  const float* vw    = (const float*)d_in[9];
  const float* outW  = (const float*)d_in[10];
  const float* outb  = (const float*)d_in[11];
  float* out = (float*)d_out;

  float* ws   = (float*)d_ws;
  const size_t SEG = (size_t)BB * TT * HH;  // 1,048,576 floats = 4 MB
  float* encH = ws;
  float* decH = ws + SEG;
  float* Abuf = ws + 2 * SEG;
  float* Pbuf = ws + 3 * SEG;

  lstm_kernel<<<4, 512, 0, stream>>>(x, eWih, eWhh, eb, dWih, dWhh, db, encH, decH);
  proj_kernel<<<1024, 256, 0, stream>>>(encH, decH, attnW, attnb, Abuf, Pbuf);
  attn_kernel<<<512, 512, 0, stream>>>(encH, decH, Abuf, Pbuf, vw, outW, outb, out);
}

// Round 8
// 432.164 us; speedup vs baseline: 1.6245x; 1.6245x over previous
//
#include <hip/hip_runtime.h>
#include <hip/hip_bf16.h>

// Problem dims
#define BB 64
#define TT 128
#define FIN 12
#define HH 128
#define BT 16    // batches per lstm block (MFMA N)
#define SROW 136 // sbuf row stride in fp16 elems: 272B/row, 16B-aligned

#define LOG2E 1.4426950408889634f
#define TWO_LOG2E 2.8853900817779268f

typedef __attribute__((ext_vector_type(8))) _Float16 f16x8;
typedef __attribute__((ext_vector_type(4))) _Float16 f16x4;
typedef __attribute__((ext_vector_type(4))) float f32x4;

#define MFMA16(a, b, c) __builtin_amdgcn_mfma_f32_16x16x32_f16((a), (b), (c), 0, 0, 0)

__device__ __forceinline__ float fexp2(float x) { return __builtin_amdgcn_exp2f(x); }
__device__ __forceinline__ float frcp(float x)  { return __builtin_amdgcn_rcpf(x); }

__device__ __forceinline__ float tanh_f(float x) {
  return 1.0f - 2.0f * frcp(1.0f + fexp2(TWO_LOG2E * x));
}
__device__ __forceinline__ float sigm_f(float x) {
  return frcp(1.0f + fexp2(-LOG2E * x));
}

#define FMA4S(acc, s, v) do { \
  acc.x = fmaf((s), (v).x, acc.x); \
  acc.y = fmaf((s), (v).y, acc.y); \
  acc.z = fmaf((s), (v).z, acc.z); \
  acc.w = fmaf((s), (v).w, acc.w); } while (0)

// ---------------------------------------------------------------------------
// K1 v8: MFMA recurrence, SINGLE-TERM fp16 (R7 post-mortem: 3-term bf16 =
// 480 MFMA/step = 2330cyc floor + 160-reg A-frags spilled to scratch ->
// 570us). fp16 11-bit mantissa: w,h,x rounded RNE, fp32 accumulate; expected
// extra error ~1e-4 (R7 measured the hi/lo path added ZERO error vs fp32, and
// threshold has 7x headroom).
// 4 blocks x 512 thr (8 waves). Per step:
//   z(512x16) = [Whh | Wih | b](512x160) @ [h; x_t; 1](160x16)
// via 16x16x32 f16 MFMA: 20 MFMA/wave/step (160/block ~ 776 cyc issue).
// A-frags: 4 gates x 5 kt x 4 VGPR = 80 regs -- fits (512,2)'s 256-reg cap,
// no spill. Wave w owns rows w*16..w*16+15 of each gate block; C layout
// (col=batch, row=quad*4+r) keeps activations/c/h fully in-lane.
// h round-trips LDS fp16 (double-buffered); 1 barrier/step.
// ---------------------------------------------------------------------------
__global__ __launch_bounds__(512, 2) void lstm_kernel(
    const float* __restrict__ x,
    const float* __restrict__ eWih, const float* __restrict__ eWhh, const float* __restrict__ eb,
    const float* __restrict__ dWih, const float* __restrict__ dWhh, const float* __restrict__ db,
    float* __restrict__ encH, float* __restrict__ decH)
{
  const int bb0  = blockIdx.x * BT;
  const int tid  = threadIdx.x;
  const int w    = tid >> 6;     // wave 0..7
  const int lane = tid & 63;
  const int bcol = lane & 15;    // batch col (B n-index, C col)
  const int quad = lane >> 4;

  __shared__ __align__(16) _Float16 sbuf[2][BT][SROW];  // 8.5 KB, h hi only

  // zero-fill sbuf (h(0)=0, pad zeros)
  {
    unsigned* p = (unsigned*)sbuf;
    for (int idx = tid; idx < (int)(sizeof(sbuf) / 4); idx += 512) p[idx] = 0;
  }

  // preload x(t=0) into regs
  float xc[8];
  {
    const float* xb = x + (size_t)(bb0 + bcol) * TT * FIN;
    if (quad == 0) {
      float4 a = *(const float4*)xb, b2 = *(const float4*)(xb + 4);
      xc[0]=a.x; xc[1]=a.y; xc[2]=a.z; xc[3]=a.w; xc[4]=b2.x; xc[5]=b2.y; xc[6]=b2.z; xc[7]=b2.w;
    } else if (quad == 1) {
      float4 a = *(const float4*)(xb + 8);
      xc[0]=a.x; xc[1]=a.y; xc[2]=a.z; xc[3]=a.w; xc[4]=0; xc[5]=0; xc[6]=0; xc[7]=0;
    } else {
      #pragma unroll
      for (int j = 0; j < 8; ++j) xc[j] = 0.0f;
    }
  }
  __syncthreads();  // sbuf zeros visible

  const int arow = w * 16 + bcol;        // A m-row within each gate block
  const int jb   = w * 16 + quad * 4;    // h rows this lane produces (C rows)

  float c0 = 0.f, c1 = 0.f, c2 = 0.f, c3 = 0.f;     // cell state
  float hp0 = 0.f, hp1 = 0.f, hp2 = 0.f, hp3 = 0.f; // h(ts-1) pending store

  #pragma unroll 1
  for (int phase = 0; phase < 2; ++phase) {
    const float* Wih  = phase ? dWih : eWih;
    const float* Whh  = phase ? dWhh : eWhh;
    const float* bias = phase ? db : eb;

    // ---- A fragments: 4 gates x 5 k-tiles, fp16 single term (80 VGPRs) ----
    f16x8 A[4][5];
    #pragma unroll
    for (int g = 0; g < 4; ++g) {
      const float* wr = Whh + (size_t)(g * HH + arow) * HH + quad * 8;
      #pragma unroll
      for (int kt = 0; kt < 4; ++kt) {
        float4 v0 = *(const float4*)(wr + kt * 32);
        float4 v1 = *(const float4*)(wr + kt * 32 + 4);
        f16x8 a;
        a[0] = (_Float16)v0.x; a[1] = (_Float16)v0.y; a[2] = (_Float16)v0.z; a[3] = (_Float16)v0.w;
        a[4] = (_Float16)v1.x; a[5] = (_Float16)v1.y; a[6] = (_Float16)v1.z; a[7] = (_Float16)v1.w;
        A[g][kt] = a;
      }
      {  // kt=4: k=128..159 -> [x-weights (12) | bias @k=140 | 0]
        float vv[8] = {0, 0, 0, 0, 0, 0, 0, 0};
        if (quad == 0) {
          const float* wir = Wih + (size_t)(g * HH + arow) * FIN;
          #pragma unroll
          for (int j = 0; j < 8; ++j) vv[j] = wir[j];
        } else if (quad == 1) {
          const float* wir = Wih + (size_t)(g * HH + arow) * FIN + 8;
          #pragma unroll
          for (int j = 0; j < 4; ++j) vv[j] = wir[j];
          vv[4] = bias[g * HH + arow];
        }
        f16x8 a;
        #pragma unroll
        for (int j = 0; j < 8; ++j) a[j] = (_Float16)vv[j];
        A[g][4] = a;
      }
    }

    #pragma unroll 1
    for (int t = 0; t < TT; ++t) {
      const int ts  = phase * TT + t;
      const int cur = ts & 1, nxt = cur ^ 1;
      __syncthreads();  // sbuf[cur] = h(ts) ready; prev reads of sbuf[nxt] done

      // 1. store h(ts-1) early (ack lands before next barrier)
      if (ts > 0) {
        const int tsp = ts - 1;
        float* Hp = (tsp >> 7) ? decH : encH;
        *(float4*)(Hp + ((size_t)(bb0 + bcol) * TT + (tsp & 127)) * HH + jb)
            = make_float4(hp0, hp1, hp2, hp3);
      }

      // 2. prefetch x for next step
      float xn[8] = {0, 0, 0, 0, 0, 0, 0, 0};
      {
        const int tn = (ts + 1) & 127;
        const float* xb = x + (size_t)(bb0 + bcol) * TT * FIN + tn * FIN;
        if (quad == 0) {
          float4 a = *(const float4*)xb, b2 = *(const float4*)(xb + 4);
          xn[0]=a.x; xn[1]=a.y; xn[2]=a.z; xn[3]=a.w; xn[4]=b2.x; xn[5]=b2.y; xn[6]=b2.z; xn[7]=b2.w;
        } else if (quad == 1) {
          float4 a = *(const float4*)(xb + 8);
          xn[0]=a.x; xn[1]=a.y; xn[2]=a.z; xn[3]=a.w;
        }
      }

      // 3. B fragment kt=4 from xc regs: [x | 1.0 @k=140 | 0]
      f16x8 bx;
      #pragma unroll
      for (int j = 0; j < 8; ++j) bx[j] = (_Float16)0.0f;
      if (quad == 0) {
        #pragma unroll
        for (int j = 0; j < 8; ++j) bx[j] = (_Float16)xc[j];
      } else if (quad == 1) {
        #pragma unroll
        for (int j = 0; j < 4; ++j) bx[j] = (_Float16)xc[j];
        bx[4] = (_Float16)1.0f;
      }

      // 4. k-streamed MFMA: 20 per wave
      f32x4 a0 = {0,0,0,0}, a1 = {0,0,0,0}, a2 = {0,0,0,0}, a3 = {0,0,0,0};
      const _Float16* sb = &sbuf[cur][bcol][quad * 8];
      #pragma unroll
      for (int kt = 0; kt < 4; ++kt) {
        f16x8 bh = *(const f16x8*)(sb + kt * 32);
        a0 = MFMA16(A[0][kt], bh, a0);
        a1 = MFMA16(A[1][kt], bh, a1);
        a2 = MFMA16(A[2][kt], bh, a2);
        a3 = MFMA16(A[3][kt], bh, a3);
      }
      a0 = MFMA16(A[0][4], bx, a0);
      a1 = MFMA16(A[1][4], bx, a1);
      a2 = MFMA16(A[2][4], bx, a2);
      a3 = MFMA16(A[3][4], bx, a3);

      // 5. activations + cell update (rows jb..jb+3, batch bcol)
      f16x4 hv;
      {
        float zi, zf, zg, zo;
        zi = sigm_f(a0[0]); zf = sigm_f(a1[0]); zg = tanh_f(a2[0]); zo = sigm_f(a3[0]);
        c0 = fmaf(zf, c0, zi * zg); hp0 = zo * tanh_f(c0); hv[0] = (_Float16)hp0;
        zi = sigm_f(a0[1]); zf = sigm_f(a1[1]); zg = tanh_f(a2[1]); zo = sigm_f(a3[1]);
        c1 = fmaf(zf, c1, zi * zg); hp1 = zo * tanh_f(c1); hv[1] = (_Float16)hp1;
        zi = sigm_f(a0[2]); zf = sigm_f(a1[2]); zg = tanh_f(a2[2]); zo = sigm_f(a3[2]);
        c2 = fmaf(zf, c2, zi * zg); hp2 = zo * tanh_f(c2); hv[2] = (_Float16)hp2;
        zi = sigm_f(a0[3]); zf = sigm_f(a1[3]); zg = tanh_f(a2[3]); zo = sigm_f(a3[3]);
        c3 = fmaf(zf, c3, zi * zg); hp3 = zo * tanh_f(c3); hv[3] = (_Float16)hp3;
      }

      // 6. write h(ts+1) fp16 to sbuf[nxt] (4 halves = 8B, 2-way banks = free)
      *(f16x4*)&sbuf[nxt][bcol][jb] = hv;

      // 7. roll x regs
      #pragma unroll
      for (int j = 0; j < 8; ++j) xc[j] = xn[j];
    }
  }
  // final store h(255)
  *(float4*)(decH + ((size_t)(bb0 + bcol) * TT + 127) * HH + jb)
      = make_float4(hp0, hp1, hp2, hp3);
}

// ---------------------------------------------------------------------------
// K2: A[b,s,h] = decH[b,s,:]·W1[h,:] + attn_b[h]   (m==0)
//     P[b,t,h] = encH[b,t,:]·W2[h,:]               (m==1)
// grid 1024 = (8 row-tiles x 64 b x 2 m), 256 threads, k-halved LDS W^T.
// ---------------------------------------------------------------------------
__global__ __launch_bounds__(256, 2) void proj_kernel(
    const float* __restrict__ encH, const float* __restrict__ decH,
    const float* __restrict__ attnW, const float* __restrict__ attnb,
    float* __restrict__ Abuf, float* __restrict__ Pbuf)
{
  const int m  = blockIdx.x & 1;
  const int b  = (blockIdx.x >> 1) & 63;
  const int r0 = (blockIdx.x >> 7) * 16;
  const int tid = threadIdx.x;

  __shared__ __align__(16) float WT[64 * 128];  // 32 KB: W^T for a k-half
  __shared__ __align__(16) float Xt[16 * 128];  // 8 KB

  const float* X = (m ? encH : decH) + ((size_t)b * TT + r0) * HH;
  const float* W = attnW + (m ? HH : 0);

  ((float4*)Xt)[tid]       = ((const float4*)X)[tid];
  ((float4*)Xt)[256 + tid] = ((const float4*)X)[256 + tid];

  const int hq = tid & 31, rr = tid >> 5;
  const int h0 = 4 * hq;

  float4 acc0, acc1;
  if (m == 0) { acc0 = *(const float4*)(attnb + h0); acc1 = acc0; }
  else        { acc0 = make_float4(0.f, 0.f, 0.f, 0.f); acc1 = acc0; }

  for (int kb = 0; kb < 2; ++kb) {
    __syncthreads();  // protect WT overwrite
    {
      int h = tid >> 1, koff = (tid & 1) * 32;
      #pragma unroll
      for (int j = 0; j < 8; ++j) {
        float4 v = *(const float4*)(W + h * 256 + kb * 64 + koff + 4 * j);
        int kp = koff + 4 * j;
        WT[(kp + 0) * 128 + h] = v.x;
        WT[(kp + 1) * 128 + h] = v.y;
        WT[(kp + 2) * 128 + h] = v.z;
        WT[(kp + 3) * 128 + h] = v.w;
      }
    }
    __syncthreads();
    const float* xr0 = Xt + (2 * rr) * 128 + kb * 64;
    const float* xr1 = xr0 + 128;
    #pragma unroll
    for (int k4 = 0; k4 < 64; k4 += 4) {
      float4 xa = *(const float4*)(xr0 + k4);
      float4 xb = *(const float4*)(xr1 + k4);
      float4 w0 = *(const float4*)&WT[(k4 + 0) * 128 + h0];
      float4 w1 = *(const float4*)&WT[(k4 + 1) * 128 + h0];
      float4 w2 = *(const float4*)&WT[(k4 + 2) * 128 + h0];
      float4 w3 = *(const float4*)&WT[(k4 + 3) * 128 + h0];
      FMA4S(acc0, xa.x, w0); FMA4S(acc0, xa.y, w1);
      FMA4S(acc0, xa.z, w2); FMA4S(acc0, xa.w, w3);
      FMA4S(acc1, xb.x, w0); FMA4S(acc1, xb.y, w1);
      FMA4S(acc1, xb.z, w2); FMA4S(acc1, xb.w, w3);
    }
  }
  float* O = (m ? Pbuf : Abuf) + ((size_t)b * TT + r0) * HH;
  *(float4*)(O + (2 * rr) * 128 + h0)     = acc0;
  *(float4*)(O + (2 * rr + 1) * 128 + h0) = acc1;
}

// ---------------------------------------------------------------------------
// K3: attention + output. Block = (b, 16 decoder steps). 512 threads.
// t halved so LDS stays < 64 KB; P transposed into LDS with XOR-quad swizzle.
// ---------------------------------------------------------------------------
__global__ __launch_bounds__(512, 2) void attn_kernel(
    const float* __restrict__ encH, const float* __restrict__ decH,
    const float* __restrict__ Abuf, const float* __restrict__ Pbuf,
    const float* __restrict__ vw, const float* __restrict__ outW,
    const float* __restrict__ outb, float* __restrict__ out)
{
  const int b  = blockIdx.x >> 3;
  const int s0 = (blockIdx.x & 7) * 16;
  const int tid = threadIdx.x;

  __shared__ __align__(16) float buf[64 * 128];    // 32 KB: P^T-half (swizzled), later encH-half
  __shared__ __align__(16) float a_lds[16 * 128];  // 8 KB: A tile, later ctx
  __shared__ __align__(16) float sc[16 * 128];     // 8 KB: scores -> weights
  __shared__ __align__(16) float dh[16 * 128];     // 8 KB: decH tile
  __shared__ __align__(16) float vl[HH];

  ((float4*)a_lds)[tid] = ((const float4*)(Abuf + ((size_t)b * TT + s0) * HH))[tid];
  ((float4*)dh)[tid]    = ((const float4*)(decH + ((size_t)b * TT + s0) * HH))[tid];
  if (tid < 32) ((float4*)vl)[tid] = ((const float4*)vw)[tid];

  const int u  = tid & 31;
  const int sl = tid >> 5;   // 0..15 decoder-step within tile
  const int uq = u & 15;     // t-quad within half
  const int uh = u >> 4;     // 0/1 h-half

  // ---- energies/scores ----
  for (int half = 0; half < 2; ++half) {
    const int tbase = half * 64;
    __syncthreads();  // prev buf use done (also covers initial staging)
    #pragma unroll
    for (int i = 0; i < 4; ++i) {
      int flat = i * 2048 + tid * 4;
      int tp = flat >> 7;        // 0..63
      int h0 = flat & 127;
      float4 v = *(const float4*)(Pbuf + ((size_t)b * TT + tbase + tp) * HH + h0);
      int tq = tp >> 2, tr = tp & 3;
      buf[(h0 + 0) * 64 + 4 * ((tq ^ ((h0 + 0) >> 2)) & 15) + tr] = v.x;
      buf[(h0 + 1) * 64 + 4 * ((tq ^ ((h0 + 1) >> 2)) & 15) + tr] = v.y;
      buf[(h0 + 2) * 64 + 4 * ((tq ^ ((h0 + 2) >> 2)) & 15) + tr] = v.z;
      buf[(h0 + 3) * 64 + 4 * ((tq ^ ((h0 + 3) >> 2)) & 15) + tr] = v.w;
    }
    __syncthreads();
    float4 acc = make_float4(0.f, 0.f, 0.f, 0.f);
    const float* arow = a_lds + sl * 128;
    #pragma unroll 8
    for (int hh = 0; hh < 64; ++hh) {
      int h = uh * 64 + hh;
      float ah = arow[h];
      float vh = vl[h];
      float4 p4 = *(const float4*)&buf[h * 64 + 4 * ((uq ^ ((h >> 2) & 15)) & 15)];
      acc.x = fmaf(vh, tanh_f(ah + p4.x), acc.x);
      acc.y = fmaf(vh, tanh_f(ah + p4.y), acc.y);
      acc.z = fmaf(vh, tanh_f(ah + p4.z), acc.z);
      acc.w = fmaf(vh, tanh_f(ah + p4.w), acc.w);
    }
    acc.x += __shfl_xor(acc.x, 16, 64);
    acc.y += __shfl_xor(acc.y, 16, 64);
    acc.z += __shfl_xor(acc.z, 16, 64);
    acc.w += __shfl_xor(acc.w, 16, 64);
    if (uh == 0) *(float4*)&sc[sl * 128 + tbase + 4 * uq] = acc;
  }
  __syncthreads();

  // ---- softmax over t (per s row; 32 lanes x f4 = 128) ----
  {
    float4 sv = *(const float4*)&sc[sl * 128 + 4 * u];
    float mx = fmaxf(fmaxf(sv.x, sv.y), fmaxf(sv.z, sv.w));
    #pragma unroll
    for (int msk = 1; msk <= 16; msk <<= 1) mx = fmaxf(mx, __shfl_xor(mx, msk, 64));
    float4 e;
    e.x = fexp2(LOG2E * (sv.x - mx));
    e.y = fexp2(LOG2E * (sv.y - mx));
    e.z = fexp2(LOG2E * (sv.z - mx));
    e.w = fexp2(LOG2E * (sv.w - mx));
    float sm = (e.x + e.y) + (e.z + e.w);
    #pragma unroll
    for (int msk = 1; msk <= 16; msk <<= 1) sm += __shfl_xor(sm, msk, 64);
    float r = frcp(sm);
    e.x *= r; e.y *= r; e.z *= r; e.w *= r;
    *(float4*)&sc[sl * 128 + 4 * u] = e;
  }

  // ---- ctx = w @ encH ----
  float4 ctx = make_float4(0.f, 0.f, 0.f, 0.f);
  const int h0c = 4 * u;
  for (int half = 0; half < 2; ++half) {
    const int tbase = half * 64;
    __syncthreads();  // buf reuse; also orders softmax writes before reads
    #pragma unroll
    for (int i = 0; i < 4; ++i) {
      int flat = i * 2048 + tid * 4;
      int tp = flat >> 7;
      int hh0 = flat & 127;
      *(float4*)&buf[tp * 128 + hh0] =
          *(const float4*)(encH + ((size_t)b * TT + tbase + tp) * HH + hh0);
    }
    __syncthreads();
    const float* wrow = sc + sl * 128 + tbase;
    #pragma unroll 8
    for (int tp = 0; tp < 64; ++tp) {
      float wt = wrow[tp];
      float4 e4 = *(const float4*)&buf[tp * 128 + h0c];
      FMA4S(ctx, wt, e4);
    }
  }
  __syncthreads();
  *(float4*)&a_lds[sl * 128 + h0c] = ctx;  // overlay A tile with ctx
  __syncthreads();

  // ---- out = [decH, ctx] @ outW^T + outb ----
  if (tid < 192) {
    int s = tid / 12, f = tid % 12;
    float acc = outb[f];
    const float4* w4 = (const float4*)(outW + f * 256);
    const float4* d4 = (const float4*)(dh + s * 128);
    const float4* c4 = (const float4*)(a_lds + s * 128);
    #pragma unroll
    for (int k = 0; k < 32; ++k) {
      float4 wv = w4[k], dv = d4[k];
      acc = fmaf(wv.x, dv.x, acc); acc = fmaf(wv.y, dv.y, acc);
      acc = fmaf(wv.z, dv.z, acc); acc = fmaf(wv.w, dv.w, acc);
    }
    #pragma unroll
    for (int k = 0; k < 32; ++k) {
      float4 wv = w4[32 + k], cv = c4[k];
      acc = fmaf(wv.x, cv.x, acc); acc = fmaf(wv.y, cv.y, acc);
      acc = fmaf(wv.z, cv.z, acc); acc = fmaf(wv.w, cv.w, acc);
    }
    out[((size_t)b * TT + s0 + s) * FIN + f] = acc;
  }
}

// ---------------------------------------------------------------------------
extern "C" void kernel_launch(void* const* d_in, const int* in_sizes, int n_in,
                              void* d_out, int out_size, void* d_ws, size_t ws_size,
                              hipStream_t stream)
{
  const float* x     = (const float*)d_in[0];
  const float* eWih  = (const float*)d_in[1];
  const float* eWhh  = (const float*)d_in[2];
  const float* eb    = (const float*)d_in[3];
  const float* dWih  = (const float*)d_in[4];
  const float* dWhh  = (const float*)d_in[5];
  const float* db    = (const float*)d_in[6];
  const float* attnW = (const float*)d_in[7];
  const float* attnb = (const float*)d_in[8];
  const float* vw    = (const float*)d_in[9];
  const float* outW  = (const float*)d_in[10];
  const float* outb  = (const float*)d_in[11];
  float* out = (float*)d_out;

  float* ws   = (float*)d_ws;
  const size_t SEG = (size_t)BB * TT * HH;  // 1,048,576 floats = 4 MB
  float* encH = ws;
  float* decH = ws + SEG;
  float* Abuf = ws + 2 * SEG;
  float* Pbuf = ws + 3 * SEG;

  lstm_kernel<<<4, 512, 0, stream>>>(x, eWih, eWhh, eb, dWih, dWhh, db, encH, decH);
  proj_kernel<<<1024, 256, 0, stream>>>(encH, decH, attnW, attnb, Abuf, Pbuf);
  attn_kernel<<<512, 512, 0, stream>>>(encH, decH, Abuf, Pbuf, vw, outW, outb, out);
}

// Round 9
// 369.525 us; speedup vs baseline: 1.8999x; 1.1695x over previous
//
#include <hip/hip_runtime.h>
#include <hip/hip_bf16.h>

// Problem dims
#define BB 64
#define TT 128
#define FIN 12
#define HH 128
#define GG 512  // 4*H

#define LOG2E 1.4426950408889634f
#define TWO_LOG2E 2.8853900817779268f

typedef float v2f __attribute__((ext_vector_type(2)));

__device__ __forceinline__ float fexp2(float x) { return __builtin_amdgcn_exp2f(x); }
__device__ __forceinline__ float frcp(float x)  { return __builtin_amdgcn_rcpf(x); }

__device__ __forceinline__ float tanh_f(float x) {
  return 1.0f - 2.0f * frcp(1.0f + fexp2(TWO_LOG2E * x));
}
__device__ __forceinline__ float sigm_f(float x) {
  return frcp(1.0f + fexp2(-LOG2E * x));
}

// VOP3P packed fp32 FMA: d.lo=fma(a.lo,b.lo,c.lo), d.hi=fma(a.hi,b.hi,c.hi).
// HIP won't auto-pack scalar fmaf chains; one instr does 2 MACs at full rate.
__device__ __forceinline__ v2f pk_fma(v2f a, v2f b, v2f c) {
  v2f d;
  asm("v_pk_fma_f32 %0, %1, %2, %3" : "=v"(d) : "v"(a), "v"(b), "v"(c));
  return d;
}

// DPP 8-lane sum (lane bits 0..2): pure VALU, no DS traffic (R5/R6 lesson).
template <int CTRL>
__device__ __forceinline__ float dpp_addstage(float v) {
  int s = __builtin_amdgcn_update_dpp(0, __float_as_int(v), CTRL, 0xF, 0xF, true);
  return v + __int_as_float(s);
}
__device__ __forceinline__ float red8(float v) {
  v = dpp_addstage<0xB1>(v);   // lane^1
  v = dpp_addstage<0x4E>(v);   // lane^2
  v = dpp_addstage<0x141>(v);  // lane^7 (row_half_mirror) -> 8-lane total
  return v;
}

#define FMA4S(acc, s, v) do { \
  acc.x = fmaf((s), (v).x, acc.x); \
  acc.y = fmaf((s), (v).y, acc.y); \
  acc.z = fmaf((s), (v).z, acc.z); \
  acc.w = fmaf((s), (v).w, acc.w); } while (0)

// ---------------------------------------------------------------------------
// K1 v9 = R6 structure (208us; VALU-issue-bound: ~1200cyc/SIMD/step of scalar
// FMA) with the 64 weight-FMAs packed into 32 v_pk_fma_f32. R8 post-mortem:
// MFMA variant concentrates all trans work on 4 CUs (2755 cyc/step) -- the
// 64-block scalar design spreads it (trans only ~320 cyc/SIMD/step here).
// Layout: thread (i = tid>>3, q = tid&7) owns all 4 gate rows of h-index i
// over k-slice [16q,16q+16); h skewed in LDS (16-float blocks padded to 20);
// DPP 8-lane reduce; q==0 lane does activations + (c,h) update; h history
// staged in LDS (32 KB), bulk-copied every 64 steps (no vm ops in step loop).
// 1 barrier/step.
// ---------------------------------------------------------------------------
__global__ __launch_bounds__(1024, 4) void lstm_kernel(
    const float* __restrict__ x,
    const float* __restrict__ eWih, const float* __restrict__ eWhh, const float* __restrict__ eb,
    const float* __restrict__ dWih, const float* __restrict__ dWhh, const float* __restrict__ db,
    float* __restrict__ encH, float* __restrict__ decH)
{
  const int b   = blockIdx.x;
  const int tid = threadIdx.x;
  const int q   = tid & 7;    // k-slice index
  const int i   = tid >> 3;   // h index 0..127

  __shared__ __align__(16) float xs[TT * FIN];     // 6 KB
  __shared__ __align__(16) float hbuf[2][160];     // skewed h, double-buffered
  __shared__ __align__(16) float hist[64 * HH];    // 32 KB: 64-step h history

  if (tid < (TT * FIN / 4))
    ((float4*)xs)[tid] = ((const float4*)(x + (size_t)b * TT * FIN))[tid];
  if (tid < 320) ((float*)hbuf)[tid] = 0.0f;
  float c = 0.0f;  // live in q==0 lanes

  const int xo   = (q < 4) ? 3 * q : 0;   // in-bounds x offset
  const float xz = (q < 4) ? 1.0f : 0.0f;

  int ts = 0;
  #pragma unroll 1
  for (int phase = 0; phase < 2; ++phase) {
    const float* Wih  = phase ? dWih : eWih;
    const float* Whh  = phase ? dWhh : eWhh;
    const float* bias = phase ? db : eb;
    float* Hout       = phase ? decH : encH;

    // recurrent weights as v2f pairs: 4 gates x 8 pairs (k = 16q + 2j)
    v2f w2[4][8];
    #pragma unroll
    for (int g = 0; g < 4; ++g)
      #pragma unroll
      for (int j = 0; j < 4; ++j) {
        float4 v = *(const float4*)(Whh + ((g * HH + i) * HH) + 16 * q + 4 * j);
        w2[g][2 * j]     = (v2f){v.x, v.y};
        w2[g][2 * j + 1] = (v2f){v.z, v.w};
      }

    // input weights: 3 columns (xo..xo+2) of each gate row; zero for q>=4
    float wx[4][3];
    #pragma unroll
    for (int g = 0; g < 4; ++g)
      #pragma unroll
      for (int j = 0; j < 3; ++j)
        wx[g][j] = Wih[(g * HH + i) * FIN + xo + j] * xz;

    const float bi = bias[i], bf = bias[HH + i], bg = bias[2 * HH + i], bo = bias[3 * HH + i];

    #pragma unroll 1
    for (int half = 0; half < 2; ++half) {
      #pragma unroll 1
      for (int tt = 0; tt < 64; ++tt, ++ts) {
        const int t = half * 64 + tt;
        __syncthreads();  // h(t) ready in hbuf[ts&1]; hist copy reads done
        const float* hb = hbuf[ts & 1] + q * 20;
        float4 h0 = *(const float4*)(hb + 0);
        float4 h1 = *(const float4*)(hb + 4);
        float4 h2 = *(const float4*)(hb + 8);
        float4 h3 = *(const float4*)(hb + 12);
        v2f hp[8];
        hp[0] = (v2f){h0.x, h0.y}; hp[1] = (v2f){h0.z, h0.w};
        hp[2] = (v2f){h1.x, h1.y}; hp[3] = (v2f){h1.z, h1.w};
        hp[4] = (v2f){h2.x, h2.y}; hp[5] = (v2f){h2.z, h2.w};
        hp[6] = (v2f){h3.x, h3.y}; hp[7] = (v2f){h3.z, h3.w};

        // x contribution (q<4 lanes carry it; others have zero weights)
        const float* xt = xs + t * FIN + xo;
        float x0 = xt[0], x1 = xt[1], x2 = xt[2];
        v2f ai2 = (v2f){wx[0][0] * x0 + wx[0][1] * x1 + wx[0][2] * x2, 0.f};
        v2f af2 = (v2f){wx[1][0] * x0 + wx[1][1] * x1 + wx[1][2] * x2, 0.f};
        v2f ag2 = (v2f){wx[2][0] * x0 + wx[2][1] * x1 + wx[2][2] * x2, 0.f};
        v2f ao2 = (v2f){wx[3][0] * x0 + wx[3][1] * x1 + wx[3][2] * x2, 0.f};

        // 32 packed FMAs = 64 MACs (was 64 scalar v_fma)
        #pragma unroll
        for (int j = 0; j < 8; ++j) {
          ai2 = pk_fma(hp[j], w2[0][j], ai2);
          af2 = pk_fma(hp[j], w2[1][j], af2);
          ag2 = pk_fma(hp[j], w2[2][j], ag2);
          ao2 = pk_fma(hp[j], w2[3][j], ao2);
        }
        float ai = ai2.x + ai2.y;
        float af = af2.x + af2.y;
        float ag = ag2.x + ag2.y;
        float ao = ao2.x + ao2.y;

        // reduce partials across the 8 q-lanes -- pure DPP (VALU)
        ai = red8(ai); af = red8(af); ag = red8(ag); ao = red8(ao);

        if (q == 0) {
          float zi = sigm_f(ai + bi);
          float zf = sigm_f(af + bf);
          float zg = tanh_f(ag + bg);
          float zo = sigm_f(ao + bo);
          c = fmaf(zf, c, zi * zg);
          float hn = zo * tanh_f(c);
          hbuf[(ts + 1) & 1][(i >> 4) * 20 + (i & 15)] = hn;
          hist[tt * HH + i] = hn;   // LDS only -- no vm op in the step loop
        }
      }
      // bulk-copy this half's history to global (64*128 floats = 2048 f4)
      __syncthreads();  // hist writes visible
      {
        float4* dst = (float4*)(Hout + ((size_t)b * TT + half * 64) * HH);
        const float4* src = (const float4*)hist;
        dst[tid]        = src[tid];
        dst[tid + 1024] = src[tid + 1024];
      }
    }
  }
}

// ---------------------------------------------------------------------------
// K2: A[b,s,h] = decH[b,s,:]·W1[h,:] + attn_b[h]   (m==0)
//     P[b,t,h] = encH[b,t,:]·W2[h,:]               (m==1)
// grid 1024 = (8 row-tiles x 64 b x 2 m), 256 threads, k-halved LDS W^T.
// ---------------------------------------------------------------------------
__global__ __launch_bounds__(256, 2) void proj_kernel(
    const float* __restrict__ encH, const float* __restrict__ decH,
    const float* __restrict__ attnW, const float* __restrict__ attnb,
    float* __restrict__ Abuf, float* __restrict__ Pbuf)
{
  const int m  = blockIdx.x & 1;
  const int b  = (blockIdx.x >> 1) & 63;
  const int r0 = (blockIdx.x >> 7) * 16;
  const int tid = threadIdx.x;

  __shared__ __align__(16) float WT[64 * 128];  // 32 KB: W^T for a k-half
  __shared__ __align__(16) float Xt[16 * 128];  // 8 KB

  const float* X = (m ? encH : decH) + ((size_t)b * TT + r0) * HH;
  const float* W = attnW + (m ? HH : 0);

  ((float4*)Xt)[tid]       = ((const float4*)X)[tid];
  ((float4*)Xt)[256 + tid] = ((const float4*)X)[256 + tid];

  const int hq = tid & 31, rr = tid >> 5;
  const int h0 = 4 * hq;

  float4 acc0, acc1;
  if (m == 0) { acc0 = *(const float4*)(attnb + h0); acc1 = acc0; }
  else        { acc0 = make_float4(0.f, 0.f, 0.f, 0.f); acc1 = acc0; }

  for (int kb = 0; kb < 2; ++kb) {
    __syncthreads();  // protect WT overwrite
    {
      int h = tid >> 1, koff = (tid & 1) * 32;
      #pragma unroll
      for (int j = 0; j < 8; ++j) {
        float4 v = *(const float4*)(W + h * 256 + kb * 64 + koff + 4 * j);
        int kp = koff + 4 * j;
        WT[(kp + 0) * 128 + h] = v.x;
        WT[(kp + 1) * 128 + h] = v.y;
        WT[(kp + 2) * 128 + h] = v.z;
        WT[(kp + 3) * 128 + h] = v.w;
      }
    }
    __syncthreads();
    const float* xr0 = Xt + (2 * rr) * 128 + kb * 64;
    const float* xr1 = xr0 + 128;
    #pragma unroll
    for (int k4 = 0; k4 < 64; k4 += 4) {
      float4 xa = *(const float4*)(xr0 + k4);
      float4 xb = *(const float4*)(xr1 + k4);
      float4 w0 = *(const float4*)&WT[(k4 + 0) * 128 + h0];
      float4 w1 = *(const float4*)&WT[(k4 + 1) * 128 + h0];
      float4 w2 = *(const float4*)&WT[(k4 + 2) * 128 + h0];
      float4 w3 = *(const float4*)&WT[(k4 + 3) * 128 + h0];
      FMA4S(acc0, xa.x, w0); FMA4S(acc0, xa.y, w1);
      FMA4S(acc0, xa.z, w2); FMA4S(acc0, xa.w, w3);
      FMA4S(acc1, xb.x, w0); FMA4S(acc1, xb.y, w1);
      FMA4S(acc1, xb.z, w2); FMA4S(acc1, xb.w, w3);
    }
  }
  float* O = (m ? Pbuf : Abuf) + ((size_t)b * TT + r0) * HH;
  *(float4*)(O + (2 * rr) * 128 + h0)     = acc0;
  *(float4*)(O + (2 * rr + 1) * 128 + h0) = acc1;
}

// ---------------------------------------------------------------------------
// K3: attention + output. Block = (b, 16 decoder steps). 512 threads.
// t halved so LDS stays < 64 KB; P transposed into LDS with XOR-quad swizzle.
// ---------------------------------------------------------------------------
__global__ __launch_bounds__(512, 2) void attn_kernel(
    const float* __restrict__ encH, const float* __restrict__ decH,
    const float* __restrict__ Abuf, const float* __restrict__ Pbuf,
    const float* __restrict__ vw, const float* __restrict__ outW,
    const float* __restrict__ outb, float* __restrict__ out)
{
  const int b  = blockIdx.x >> 3;
  const int s0 = (blockIdx.x & 7) * 16;
  const int tid = threadIdx.x;

  __shared__ __align__(16) float buf[64 * 128];    // 32 KB: P^T-half (swizzled), later encH-half
  __shared__ __align__(16) float a_lds[16 * 128];  // 8 KB: A tile, later ctx
  __shared__ __align__(16) float sc[16 * 128];     // 8 KB: scores -> weights
  __shared__ __align__(16) float dh[16 * 128];     // 8 KB: decH tile
  __shared__ __align__(16) float vl[HH];

  ((float4*)a_lds)[tid] = ((const float4*)(Abuf + ((size_t)b * TT + s0) * HH))[tid];
  ((float4*)dh)[tid]    = ((const float4*)(decH + ((size_t)b * TT + s0) * HH))[tid];
  if (tid < 32) ((float4*)vl)[tid] = ((const float4*)vw)[tid];

  const int u  = tid & 31;
  const int sl = tid >> 5;   // 0..15 decoder-step within tile
  const int uq = u & 15;     // t-quad within half
  const int uh = u >> 4;     // 0/1 h-half

  // ---- energies/scores ----
  for (int half = 0; half < 2; ++half) {
    const int tbase = half * 64;
    __syncthreads();  // prev buf use done (also covers initial staging)
    #pragma unroll
    for (int i = 0; i < 4; ++i) {
      int flat = i * 2048 + tid * 4;
      int tp = flat >> 7;        // 0..63
      int h0 = flat & 127;
      float4 v = *(const float4*)(Pbuf + ((size_t)b * TT + tbase + tp) * HH + h0);
      int tq = tp >> 2, tr = tp & 3;
      buf[(h0 + 0) * 64 + 4 * ((tq ^ ((h0 + 0) >> 2)) & 15) + tr] = v.x;
      buf[(h0 + 1) * 64 + 4 * ((tq ^ ((h0 + 1) >> 2)) & 15) + tr] = v.y;
      buf[(h0 + 2) * 64 + 4 * ((tq ^ ((h0 + 2) >> 2)) & 15) + tr] = v.z;
      buf[(h0 + 3) * 64 + 4 * ((tq ^ ((h0 + 3) >> 2)) & 15) + tr] = v.w;
    }
    __syncthreads();
    float4 acc = make_float4(0.f, 0.f, 0.f, 0.f);
    const float* arow = a_lds + sl * 128;
    #pragma unroll 8
    for (int hh = 0; hh < 64; ++hh) {
      int h = uh * 64 + hh;
      float ah = arow[h];
      float vh = vl[h];
      float4 p4 = *(const float4*)&buf[h * 64 + 4 * ((uq ^ ((h >> 2) & 15)) & 15)];
      acc.x = fmaf(vh, tanh_f(ah + p4.x), acc.x);
      acc.y = fmaf(vh, tanh_f(ah + p4.y), acc.y);
      acc.z = fmaf(vh, tanh_f(ah + p4.z), acc.z);
      acc.w = fmaf(vh, tanh_f(ah + p4.w), acc.w);
    }
    acc.x += __shfl_xor(acc.x, 16, 64);
    acc.y += __shfl_xor(acc.y, 16, 64);
    acc.z += __shfl_xor(acc.z, 16, 64);
    acc.w += __shfl_xor(acc.w, 16, 64);
    if (uh == 0) *(float4*)&sc[sl * 128 + tbase + 4 * uq] = acc;
  }
  __syncthreads();

  // ---- softmax over t (per s row; 32 lanes x f4 = 128) ----
  {
    float4 sv = *(const float4*)&sc[sl * 128 + 4 * u];
    float mx = fmaxf(fmaxf(sv.x, sv.y), fmaxf(sv.z, sv.w));
    #pragma unroll
    for (int msk = 1; msk <= 16; msk <<= 1) mx = fmaxf(mx, __shfl_xor(mx, msk, 64));
    float4 e;
    e.x = fexp2(LOG2E * (sv.x - mx));
    e.y = fexp2(LOG2E * (sv.y - mx));
    e.z = fexp2(LOG2E * (sv.z - mx));
    e.w = fexp2(LOG2E * (sv.w - mx));
    float sm = (e.x + e.y) + (e.z + e.w);
    #pragma unroll
    for (int msk = 1; msk <= 16; msk <<= 1) sm += __shfl_xor(sm, msk, 64);
    float r = frcp(sm);
    e.x *= r; e.y *= r; e.z *= r; e.w *= r;
    *(float4*)&sc[sl * 128 + 4 * u] = e;
  }

  // ---- ctx = w @ encH ----
  float4 ctx = make_float4(0.f, 0.f, 0.f, 0.f);
  const int h0c = 4 * u;
  for (int half = 0; half < 2; ++half) {
    const int tbase = half * 64;
    __syncthreads();  // buf reuse; also orders softmax writes before reads
    #pragma unroll
    for (int i = 0; i < 4; ++i) {
      int flat = i * 2048 + tid * 4;
      int tp = flat >> 7;
      int hh0 = flat & 127;
      *(float4*)&buf[tp * 128 + hh0] =
          *(const float4*)(encH + ((size_t)b * TT + tbase + tp) * HH + hh0);
    }
    __syncthreads();
    const float* wrow = sc + sl * 128 + tbase;
    #pragma unroll 8
    for (int tp = 0; tp < 64; ++tp) {
      float wt = wrow[tp];
      float4 e4 = *(const float4*)&buf[tp * 128 + h0c];
      FMA4S(ctx, wt, e4);
    }
  }
  __syncthreads();
  *(float4*)&a_lds[sl * 128 + h0c] = ctx;  // overlay A tile with ctx
  __syncthreads();

  // ---- out = [decH, ctx] @ outW^T + outb ----
  if (tid < 192) {
    int s = tid / 12, f = tid % 12;
    float acc = outb[f];
    const float4* w4 = (const float4*)(outW + f * 256);
    const float4* d4 = (const float4*)(dh + s * 128);
    const float4* c4 = (const float4*)(a_lds + s * 128);
    #pragma unroll
    for (int k = 0; k < 32; ++k) {
      float4 wv = w4[k], dv = d4[k];
      acc = fmaf(wv.x, dv.x, acc); acc = fmaf(wv.y, dv.y, acc);
      acc = fmaf(wv.z, dv.z, acc); acc = fmaf(wv.w, dv.w, acc);
    }
    #pragma unroll
    for (int k = 0; k < 32; ++k) {
      float4 wv = w4[32 + k], cv = c4[k];
      acc = fmaf(wv.x, cv.x, acc); acc = fmaf(wv.y, cv.y, acc);
      acc = fmaf(wv.z, cv.z, acc); acc = fmaf(wv.w, cv.w, acc);
    }
    out[((size_t)b * TT + s0 + s) * FIN + f] = acc;
  }
}

// ---------------------------------------------------------------------------
extern "C" void kernel_launch(void* const* d_in, const int* in_sizes, int n_in,
                              void* d_out, int out_size, void* d_ws, size_t ws_size,
                              hipStream_t stream)
{
  const float* x     = (const float*)d_in[0];
  const float* eWih  = (const float*)d_in[1];
  const float* eWhh  = (const float*)d_in[2];
  const float* eb    = (const float*)d_in[3];
  const float* dWih  = (const float*)d_in[4];
  const float* dWhh  = (const float*)d_in[5];
  const float* db    = (const float*)d_in[6];
  const float* attnW = (const float*)d_in[7];
  const float* attnb = (const float*)d_in[8];
  const float* vw    = (const float*)d_in[9];
  const float* outW  = (const float*)d_in[10];
  const float* outb  = (const float*)d_in[11];
  float* out = (float*)d_out;

  float* ws   = (float*)d_ws;
  const size_t SEG = (size_t)BB * TT * HH;  // 1,048,576 floats = 4 MB
  float* encH = ws;
  float* decH = ws + SEG;
  float* Abuf = ws + 2 * SEG;
  float* Pbuf = ws + 3 * SEG;

  lstm_kernel<<<64, 1024, 0, stream>>>(x, eWih, eWhh, eb, dWih, dWhh, db, encH, decH);
  proj_kernel<<<1024, 256, 0, stream>>>(encH, decH, attnW, attnb, Abuf, Pbuf);
  attn_kernel<<<512, 512, 0, stream>>>(encH, decH, Abuf, Pbuf, vw, outW, outb, out);
}

// Round 10
// 361.843 us; speedup vs baseline: 1.9403x; 1.0212x over previous
//
#include <hip/hip_runtime.h>
#include <hip/hip_bf16.h>

// Problem dims
#define BB 64
#define TT 128
#define FIN 12
#define HH 128
#define GG 512  // 4*H

#define LOG2E 1.4426950408889634f
#define TWO_LOG2E 2.8853900817779268f

typedef float v2f __attribute__((ext_vector_type(2)));

__device__ __forceinline__ float fexp2(float x) { return __builtin_amdgcn_exp2f(x); }
__device__ __forceinline__ float frcp(float x)  { return __builtin_amdgcn_rcpf(x); }

__device__ __forceinline__ float tanh_f(float x) {
  return 1.0f - 2.0f * frcp(1.0f + fexp2(TWO_LOG2E * x));
}
__device__ __forceinline__ float sigm_f(float x) {
  return frcp(1.0f + fexp2(-LOG2E * x));
}

// DPP 8-lane sum (lane bits 0..2): pure VALU, no DS traffic (R5/R6 lesson).
template <int CTRL>
__device__ __forceinline__ float dpp_addstage(float v) {
  int s = __builtin_amdgcn_update_dpp(0, __float_as_int(v), CTRL, 0xF, 0xF, true);
  return v + __int_as_float(s);
}
__device__ __forceinline__ float red8(float v) {
  v = dpp_addstage<0xB1>(v);   // lane^1
  v = dpp_addstage<0x4E>(v);   // lane^2
  v = dpp_addstage<0x141>(v);  // lane^7 (row_half_mirror) -> 8-lane total
  return v;
}

#define FMA4S(acc, s, v) do { \
  acc.x = fmaf((s), (v).x, acc.x); \
  acc.y = fmaf((s), (v).y, acc.y); \
  acc.z = fmaf((s), (v).z, acc.z); \
  acc.w = fmaf((s), (v).w, acc.w); } while (0)

// ---------------------------------------------------------------------------
// K1 v10 = R6 structure (208us baseline) with the 64 weight-MACs expressed as
// 32 float2 elementwise-fma -- LLVM lowers these to v_pk_fma_f32 while keeping
// scheduling freedom (R9 lesson: volatile-asm pk_fma regressed 208->238 by
// walling off the scheduler; benign fallback here is plain scalar codegen).
// Layout: thread (i = tid>>3, q = tid&7) owns all 4 gate rows of h-index i
// over k-slice [16q,16q+16); h skewed in LDS (16-float blocks padded to 20);
// DPP 8-lane reduce; q==0 lane does activations + (c,h) update; h history
// staged in LDS (32 KB), bulk-copied every 64 steps (no vm ops in step loop).
// 1 barrier/step.
// ---------------------------------------------------------------------------
__global__ __launch_bounds__(1024, 4) void lstm_kernel(
    const float* __restrict__ x,
    const float* __restrict__ eWih, const float* __restrict__ eWhh, const float* __restrict__ eb,
    const float* __restrict__ dWih, const float* __restrict__ dWhh, const float* __restrict__ db,
    float* __restrict__ encH, float* __restrict__ decH)
{
  const int b   = blockIdx.x;
  const int tid = threadIdx.x;
  const int q   = tid & 7;    // k-slice index
  const int i   = tid >> 3;   // h index 0..127

  __shared__ __align__(16) float xs[TT * FIN];     // 6 KB
  __shared__ __align__(16) float hbuf[2][160];     // skewed h, double-buffered
  __shared__ __align__(16) float hist[64 * HH];    // 32 KB: 64-step h history

  if (tid < (TT * FIN / 4))
    ((float4*)xs)[tid] = ((const float4*)(x + (size_t)b * TT * FIN))[tid];
  if (tid < 320) ((float*)hbuf)[tid] = 0.0f;
  float c = 0.0f;  // live in q==0 lanes

  const int xo   = (q < 4) ? 3 * q : 0;   // in-bounds x offset
  const float xz = (q < 4) ? 1.0f : 0.0f;

  int ts = 0;
  #pragma unroll 1
  for (int phase = 0; phase < 2; ++phase) {
    const float* Wih  = phase ? dWih : eWih;
    const float* Whh  = phase ? dWhh : eWhh;
    const float* bias = phase ? db : eb;
    float* Hout       = phase ? decH : encH;

    // recurrent weights as v2f pairs: 4 gates x 8 pairs (k = 16q + 2j)
    v2f w2[4][8];
    #pragma unroll
    for (int g = 0; g < 4; ++g)
      #pragma unroll
      for (int j = 0; j < 4; ++j) {
        float4 v = *(const float4*)(Whh + ((g * HH + i) * HH) + 16 * q + 4 * j);
        w2[g][2 * j]     = (v2f){v.x, v.y};
        w2[g][2 * j + 1] = (v2f){v.z, v.w};
      }

    // input weights: 3 columns (xo..xo+2) of each gate row; zero for q>=4
    float wx[4][3];
    #pragma unroll
    for (int g = 0; g < 4; ++g)
      #pragma unroll
      for (int j = 0; j < 3; ++j)
        wx[g][j] = Wih[(g * HH + i) * FIN + xo + j] * xz;

    const float bi = bias[i], bf = bias[HH + i], bg = bias[2 * HH + i], bo = bias[3 * HH + i];

    #pragma unroll 1
    for (int half = 0; half < 2; ++half) {
      #pragma unroll 1
      for (int tt = 0; tt < 64; ++tt, ++ts) {
        const int t = half * 64 + tt;
        __syncthreads();  // h(t) ready in hbuf[ts&1]; hist copy reads done
        const float* hb = hbuf[ts & 1] + q * 20;
        float4 h0 = *(const float4*)(hb + 0);
        float4 h1 = *(const float4*)(hb + 4);
        float4 h2 = *(const float4*)(hb + 8);
        float4 h3 = *(const float4*)(hb + 12);
        v2f hp[8];
        hp[0] = (v2f){h0.x, h0.y}; hp[1] = (v2f){h0.z, h0.w};
        hp[2] = (v2f){h1.x, h1.y}; hp[3] = (v2f){h1.z, h1.w};
        hp[4] = (v2f){h2.x, h2.y}; hp[5] = (v2f){h2.z, h2.w};
        hp[6] = (v2f){h3.x, h3.y}; hp[7] = (v2f){h3.z, h3.w};

        // x contribution (q<4 lanes carry it; others have zero weights)
        const float* xt = xs + t * FIN + xo;
        float x0 = xt[0], x1 = xt[1], x2 = xt[2];
        v2f ai2 = (v2f){wx[0][0] * x0 + wx[0][1] * x1 + wx[0][2] * x2, 0.f};
        v2f af2 = (v2f){wx[1][0] * x0 + wx[1][1] * x1 + wx[1][2] * x2, 0.f};
        v2f ag2 = (v2f){wx[2][0] * x0 + wx[2][1] * x1 + wx[2][2] * x2, 0.f};
        v2f ao2 = (v2f){wx[3][0] * x0 + wx[3][1] * x1 + wx[3][2] * x2, 0.f};

        // 32 packed FMAs = 64 MACs (compiler-scheduled v_pk_fma_f32)
        #pragma unroll
        for (int j = 0; j < 8; ++j) {
          ai2 = __builtin_elementwise_fma(hp[j], w2[0][j], ai2);
          af2 = __builtin_elementwise_fma(hp[j], w2[1][j], af2);
          ag2 = __builtin_elementwise_fma(hp[j], w2[2][j], ag2);
          ao2 = __builtin_elementwise_fma(hp[j], w2[3][j], ao2);
        }
        float ai = ai2.x + ai2.y;
        float af = af2.x + af2.y;
        float ag = ag2.x + ag2.y;
        float ao = ao2.x + ao2.y;

        // reduce partials across the 8 q-lanes -- pure DPP (VALU)
        ai = red8(ai); af = red8(af); ag = red8(ag); ao = red8(ao);

        if (q == 0) {
          float zi = sigm_f(ai + bi);
          float zf = sigm_f(af + bf);
          float zg = tanh_f(ag + bg);
          float zo = sigm_f(ao + bo);
          c = fmaf(zf, c, zi * zg);
          float hn = zo * tanh_f(c);
          hbuf[(ts + 1) & 1][(i >> 4) * 20 + (i & 15)] = hn;
          hist[tt * HH + i] = hn;   // LDS only -- no vm op in the step loop
        }
      }
      // bulk-copy this half's history to global (64*128 floats = 2048 f4)
      __syncthreads();  // hist writes visible
      {
        float4* dst = (float4*)(Hout + ((size_t)b * TT + half * 64) * HH);
        const float4* src = (const float4*)hist;
        dst[tid]        = src[tid];
        dst[tid + 1024] = src[tid + 1024];
      }
    }
  }
}

// ---------------------------------------------------------------------------
// K2: A'[b,s,h] = 2log2e*(decH[b,s,:]·W1[h,:] + attn_b[h])   (m==0)
//     P'[b,t,h] = 2log2e*(encH[b,t,:]·W2[h,:])               (m==1)
// Pre-scaled by 2log2e so K3's energy tanh uses exp2 directly (saves one
// v_mul per energy cell -- 134M cells). grid 1024, 256 threads.
// ---------------------------------------------------------------------------
__global__ __launch_bounds__(256, 2) void proj_kernel(
    const float* __restrict__ encH, const float* __restrict__ decH,
    const float* __restrict__ attnW, const float* __restrict__ attnb,
    float* __restrict__ Abuf, float* __restrict__ Pbuf)
{
  const int m  = blockIdx.x & 1;
  const int b  = (blockIdx.x >> 1) & 63;
  const int r0 = (blockIdx.x >> 7) * 16;
  const int tid = threadIdx.x;

  __shared__ __align__(16) float WT[64 * 128];  // 32 KB: W^T for a k-half
  __shared__ __align__(16) float Xt[16 * 128];  // 8 KB

  const float* X = (m ? encH : decH) + ((size_t)b * TT + r0) * HH;
  const float* W = attnW + (m ? HH : 0);

  ((float4*)Xt)[tid]       = ((const float4*)X)[tid];
  ((float4*)Xt)[256 + tid] = ((const float4*)X)[256 + tid];

  const int hq = tid & 31, rr = tid >> 5;
  const int h0 = 4 * hq;

  float4 acc0, acc1;
  if (m == 0) { acc0 = *(const float4*)(attnb + h0); acc1 = acc0; }
  else        { acc0 = make_float4(0.f, 0.f, 0.f, 0.f); acc1 = acc0; }

  for (int kb = 0; kb < 2; ++kb) {
    __syncthreads();  // protect WT overwrite
    {
      int h = tid >> 1, koff = (tid & 1) * 32;
      #pragma unroll
      for (int j = 0; j < 8; ++j) {
        float4 v = *(const float4*)(W + h * 256 + kb * 64 + koff + 4 * j);
        int kp = koff + 4 * j;
        WT[(kp + 0) * 128 + h] = v.x;
        WT[(kp + 1) * 128 + h] = v.y;
        WT[(kp + 2) * 128 + h] = v.z;
        WT[(kp + 3) * 128 + h] = v.w;
      }
    }
    __syncthreads();
    const float* xr0 = Xt + (2 * rr) * 128 + kb * 64;
    const float* xr1 = xr0 + 128;
    #pragma unroll
    for (int k4 = 0; k4 < 64; k4 += 4) {
      float4 xa = *(const float4*)(xr0 + k4);
      float4 xb = *(const float4*)(xr1 + k4);
      float4 w0 = *(const float4*)&WT[(k4 + 0) * 128 + h0];
      float4 w1 = *(const float4*)&WT[(k4 + 1) * 128 + h0];
      float4 w2 = *(const float4*)&WT[(k4 + 2) * 128 + h0];
      float4 w3 = *(const float4*)&WT[(k4 + 3) * 128 + h0];
      FMA4S(acc0, xa.x, w0); FMA4S(acc0, xa.y, w1);
      FMA4S(acc0, xa.z, w2); FMA4S(acc0, xa.w, w3);
      FMA4S(acc1, xb.x, w0); FMA4S(acc1, xb.y, w1);
      FMA4S(acc1, xb.z, w2); FMA4S(acc1, xb.w, w3);
    }
  }
  // pre-scale for K3's exp2-based tanh
  acc0.x *= TWO_LOG2E; acc0.y *= TWO_LOG2E; acc0.z *= TWO_LOG2E; acc0.w *= TWO_LOG2E;
  acc1.x *= TWO_LOG2E; acc1.y *= TWO_LOG2E; acc1.z *= TWO_LOG2E; acc1.w *= TWO_LOG2E;
  float* O = (m ? Pbuf : Abuf) + ((size_t)b * TT + r0) * HH;
  *(float4*)(O + (2 * rr) * 128 + h0)     = acc0;
  *(float4*)(O + (2 * rr + 1) * 128 + h0) = acc1;
}

// ---------------------------------------------------------------------------
// K3: attention + output. Block = (b, 16 decoder steps). 512 threads.
// A'/P' arrive pre-scaled by 2log2e: energy tanh = 1 - 2*rcp(1+exp2(A'+P')).
// ---------------------------------------------------------------------------
__global__ __launch_bounds__(512, 2) void attn_kernel(
    const float* __restrict__ encH, const float* __restrict__ decH,
    const float* __restrict__ Abuf, const float* __restrict__ Pbuf,
    const float* __restrict__ vw, const float* __restrict__ outW,
    const float* __restrict__ outb, float* __restrict__ out)
{
  const int b  = blockIdx.x >> 3;
  const int s0 = (blockIdx.x & 7) * 16;
  const int tid = threadIdx.x;

  __shared__ __align__(16) float buf[64 * 128];    // 32 KB: P'^T-half (swizzled), later encH-half
  __shared__ __align__(16) float a_lds[16 * 128];  // 8 KB: A' tile, later ctx
  __shared__ __align__(16) float sc[16 * 128];     // 8 KB: scores -> weights
  __shared__ __align__(16) float dh[16 * 128];     // 8 KB: decH tile
  __shared__ __align__(16) float vl[HH];

  ((float4*)a_lds)[tid] = ((const float4*)(Abuf + ((size_t)b * TT + s0) * HH))[tid];
  ((float4*)dh)[tid]    = ((const float4*)(decH + ((size_t)b * TT + s0) * HH))[tid];
  if (tid < 32) ((float4*)vl)[tid] = ((const float4*)vw)[tid];

  const int u  = tid & 31;
  const int sl = tid >> 5;   // 0..15 decoder-step within tile
  const int uq = u & 15;     // t-quad within half
  const int uh = u >> 4;     // 0/1 h-half

  // ---- energies/scores ----
  for (int half = 0; half < 2; ++half) {
    const int tbase = half * 64;
    __syncthreads();  // prev buf use done (also covers initial staging)
    #pragma unroll
    for (int i = 0; i < 4; ++i) {
      int flat = i * 2048 + tid * 4;
      int tp = flat >> 7;        // 0..63
      int h0 = flat & 127;
      float4 v = *(const float4*)(Pbuf + ((size_t)b * TT + tbase + tp) * HH + h0);
      int tq = tp >> 2, tr = tp & 3;
      buf[(h0 + 0) * 64 + 4 * ((tq ^ ((h0 + 0) >> 2)) & 15) + tr] = v.x;
      buf[(h0 + 1) * 64 + 4 * ((tq ^ ((h0 + 1) >> 2)) & 15) + tr] = v.y;
      buf[(h0 + 2) * 64 + 4 * ((tq ^ ((h0 + 2) >> 2)) & 15) + tr] = v.z;
      buf[(h0 + 3) * 64 + 4 * ((tq ^ ((h0 + 3) >> 2)) & 15) + tr] = v.w;
    }
    __syncthreads();
    float4 acc = make_float4(0.f, 0.f, 0.f, 0.f);
    const float* arow = a_lds + sl * 128;
    #pragma unroll 8
    for (int hh = 0; hh < 64; ++hh) {
      int h = uh * 64 + hh;
      float ah = arow[h];
      float vh = vl[h];
      float4 p4 = *(const float4*)&buf[h * 64 + 4 * ((uq ^ ((h >> 2) & 15)) & 15)];
      // tanh via pre-scaled args: e = 1 - 2*rcp(1+exp2(ah+p))
      float e0 = 1.0f - 2.0f * frcp(1.0f + fexp2(ah + p4.x));
      float e1 = 1.0f - 2.0f * frcp(1.0f + fexp2(ah + p4.y));
      float e2 = 1.0f - 2.0f * frcp(1.0f + fexp2(ah + p4.z));
      float e3 = 1.0f - 2.0f * frcp(1.0f + fexp2(ah + p4.w));
      acc.x = fmaf(vh, e0, acc.x);
      acc.y = fmaf(vh, e1, acc.y);
      acc.z = fmaf(vh, e2, acc.z);
      acc.w = fmaf(vh, e3, acc.w);
    }
    acc.x += __shfl_xor(acc.x, 16, 64);
    acc.y += __shfl_xor(acc.y, 16, 64);
    acc.z += __shfl_xor(acc.z, 16, 64);
    acc.w += __shfl_xor(acc.w, 16, 64);
    if (uh == 0) *(float4*)&sc[sl * 128 + tbase + 4 * uq] = acc;
  }
  __syncthreads();

  // ---- softmax over t (per s row; 32 lanes x f4 = 128) ----
  {
    float4 sv = *(const float4*)&sc[sl * 128 + 4 * u];
    float mx = fmaxf(fmaxf(sv.x, sv.y), fmaxf(sv.z, sv.w));
    #pragma unroll
    for (int msk = 1; msk <= 16; msk <<= 1) mx = fmaxf(mx, __shfl_xor(mx, msk, 64));
    float4 e;
    e.x = fexp2(LOG2E * (sv.x - mx));
    e.y = fexp2(LOG2E * (sv.y - mx));
    e.z = fexp2(LOG2E * (sv.z - mx));
    e.w = fexp2(LOG2E * (sv.w - mx));
    float sm = (e.x + e.y) + (e.z + e.w);
    #pragma unroll
    for (int msk = 1; msk <= 16; msk <<= 1) sm += __shfl_xor(sm, msk, 64);
    float r = frcp(sm);
    e.x *= r; e.y *= r; e.z *= r; e.w *= r;
    *(float4*)&sc[sl * 128 + 4 * u] = e;
  }

  // ---- ctx = w @ encH ----
  float4 ctx = make_float4(0.f, 0.f, 0.f, 0.f);
  const int h0c = 4 * u;
  for (int half = 0; half < 2; ++half) {
    const int tbase = half * 64;
    __syncthreads();  // buf reuse; also orders softmax writes before reads
    #pragma unroll
    for (int i = 0; i < 4; ++i) {
      int flat = i * 2048 + tid * 4;
      int tp = flat >> 7;
      int hh0 = flat & 127;
      *(float4*)&buf[tp * 128 + hh0] =
          *(const float4*)(encH + ((size_t)b * TT + tbase + tp) * HH + hh0);
    }
    __syncthreads();
    const float* wrow = sc + sl * 128 + tbase;
    #pragma unroll 8
    for (int tp = 0; tp < 64; ++tp) {
      float wt = wrow[tp];
      float4 e4 = *(const float4*)&buf[tp * 128 + h0c];
      FMA4S(ctx, wt, e4);
    }
  }
  __syncthreads();
  *(float4*)&a_lds[sl * 128 + h0c] = ctx;  // overlay A tile with ctx
  __syncthreads();

  // ---- out = [decH, ctx] @ outW^T + outb ----
  if (tid < 192) {
    int s = tid / 12, f = tid % 12;
    float acc = outb[f];
    const float4* w4 = (const float4*)(outW + f * 256);
    const float4* d4 = (const float4*)(dh + s * 128);
    const float4* c4 = (const float4*)(a_lds + s * 128);
    #pragma unroll
    for (int k = 0; k < 32; ++k) {
      float4 wv = w4[k], dv = d4[k];
      acc = fmaf(wv.x, dv.x, acc); acc = fmaf(wv.y, dv.y, acc);
      acc = fmaf(wv.z, dv.z, acc); acc = fmaf(wv.w, dv.w, acc);
    }
    #pragma unroll
    for (int k = 0; k < 32; ++k) {
      float4 wv = w4[32 + k], cv = c4[k];
      acc = fmaf(wv.x, cv.x, acc); acc = fmaf(wv.y, cv.y, acc);
      acc = fmaf(wv.z, cv.z, acc); acc = fmaf(wv.w, cv.w, acc);
    }
    out[((size_t)b * TT + s0 + s) * FIN + f] = acc;
  }
}

// ---------------------------------------------------------------------------
extern "C" void kernel_launch(void* const* d_in, const int* in_sizes, int n_in,
                              void* d_out, int out_size, void* d_ws, size_t ws_size,
                              hipStream_t stream)
{
  const float* x     = (const float*)d_in[0];
  const float* eWih  = (const float*)d_in[1];
  const float* eWhh  = (const float*)d_in[2];
  const float* eb    = (const float*)d_in[3];
  const float* dWih  = (const float*)d_in[4];
  const float* dWhh  = (const float*)d_in[5];
  const float* db    = (const float*)d_in[6];
  const float* attnW = (const float*)d_in[7];
  const float* attnb = (const float*)d_in[8];
  const float* vw    = (const float*)d_in[9];
  const float* outW  = (const float*)d_in[10];
  const float* outb  = (const float*)d_in[11];
  float* out = (float*)d_out;

  float* ws   = (float*)d_ws;
  const size_t SEG = (size_t)BB * TT * HH;  // 1,048,576 floats = 4 MB
  float* encH = ws;
  float* decH = ws + SEG;
  float* Abuf = ws + 2 * SEG;
  float* Pbuf = ws + 3 * SEG;

  lstm_kernel<<<64, 1024, 0, stream>>>(x, eWih, eWhh, eb, dWih, dWhh, db, encH, decH);
  proj_kernel<<<1024, 256, 0, stream>>>(encH, decH, attnW, attnb, Abuf, Pbuf);
  attn_kernel<<<512, 512, 0, stream>>>(encH, decH, Abuf, Pbuf, vw, outW, outb, out);
}